// Round 5
// baseline (260.753 us; speedup 1.0000x reference)
//
#include <hip/hip_runtime.h>
#include <math.h>

#define NB 8
#define NC 3
#define NH 1024
#define NW 1024
#define EPS 1e-6f

#define WS_PLANE ((size_t)NB * NH * NW)          // elems per H plane (8.39M)

// ============================ PASS A: horizontal ============================
// Block = 256 threads = one full image row (float4/lane), ROWS_A=4 rows/block.
// grid: 8 batches * 256 rowgroups = 2048 blocks.
// LDS per plane: [8 zero | 1024 | 8 zero] = 1040 floats; col c <-> index 8+c.
// Lane t owns cols 4t..4t+3: writes f4 at idx 8+4t (16B aligned).
// H window +-5: reads wm1@[4t+3], A(f4)@[4t+4], own B in regs, C(f4)@[4t+12],
// wp@[4t+16] -> sliding 11-tap, 4 outputs. No ring, no vertical redundancy.
__global__ __launch_bounds__(256, 4)
void lcs_hpass(const float* __restrict__ x, const float* __restrict__ y,
               float* __restrict__ ws) {
    __shared__ __align__(16) float Pp[3][1040];

    const int t   = threadIdx.x;                 // 0..255
    const int bid = blockIdx.x;
    const int b   = bid >> 8;                    // batch
    const int rg  = bid & 255;                   // row group (4 rows)

    // zero the horizontal pads once
    #pragma unroll
    for (int p = 0; p < 3; ++p) {
        if (t < 8)  Pp[p][t] = 0.f;
        if (t < 8)  Pp[p][1032 + t] = 0.f;
    }

    const size_t chan = (size_t)NH * NW;
    const float* xb = x + (size_t)b * NC * chan;
    const float* yb = y + (size_t)b * NC * chan;
    float* wsb = ws + (size_t)b * chan;          // + p*WS_PLANE per plane

    for (int rr = 0; rr < 4; ++rr) {
        const int row = rg * 4 + rr;
        const size_t ro = (size_t)row * NW + 4 * t;

        // ---- channel-reduced products for this lane's 4 cols ----
        float4 pxx = make_float4(0.f,0.f,0.f,0.f), pyy = pxx, pxy = pxx;
        #pragma unroll
        for (int c = 0; c < 3; ++c) {
            const float4 fx = *(const float4*)(xb + c * chan + ro);
            const float4 fy = *(const float4*)(yb + c * chan + ro);
            pxx.x += fx.x*fx.x; pxx.y += fx.y*fx.y; pxx.z += fx.z*fx.z; pxx.w += fx.w*fx.w;
            pyy.x += fy.x*fy.x; pyy.y += fy.y*fy.y; pyy.z += fy.z*fy.z; pyy.w += fy.w*fy.w;
            pxy.x += fx.x*fy.x; pxy.y += fx.y*fy.y; pxy.z += fx.z*fy.z; pxy.w += fx.w*fy.w;
        }

        __syncthreads();                         // prev row's readers done (also covers pad init)
        *(float4*)&Pp[0][8 + 4*t] = pxx;
        *(float4*)&Pp[1][8 + 4*t] = pyy;
        *(float4*)&Pp[2][8 + 4*t] = pxy;
        __syncthreads();                         // writes visible to neighbor lanes/waves

        // ---- horizontal 11-tap, 4 cols per lane (own products = B in regs) ----
        const float4 own[3] = {pxx, pyy, pxy};
        #pragma unroll
        for (int p = 0; p < 3; ++p) {
            const float* q = &Pp[p][0];
            const float  wm1 = q[4*t + 3];                    // col 4t-5
            const float4 A   = *(const float4*)(q + 4*t + 4); // cols 4t-4..4t-1
            const float4 B   = own[p];                        // cols 4t..4t+3
            const float4 C   = *(const float4*)(q + 4*t + 12);// cols 4t+4..4t+7
            const float  wp  = q[4*t + 16];                   // col 4t+8
            float4 h;
            h.x = wm1 + ((A.x + A.y) + (A.z + A.w))
                      + ((B.x + B.y) + (B.z + B.w)) + (C.x + C.y);
            h.y = h.x - wm1 + C.z;
            h.z = h.y - A.x + C.w;
            h.w = h.z - A.y + wp;
            *(float4*)(wsb + (size_t)p * WS_PLANE + ro) = h;
        }
    }
}

// ============================ PASS B: vertical ==============================
// 1 col/lane, 256-thr blocks (256 cols), CHB=32 output rows/block.
// grid: 8 batches * 4 colgroups * 32 rowchunks = 1024 blocks.
// Ring = 3 planes x 11 scalars = 33 VGPR -> ~50 total -> 4 waves/SIMD.
#define CHB 32
#define KSB (CHB + 10)      // 42 H rows per chunk

__global__ __launch_bounds__(256, 4)
void lcs_vpass(const float* __restrict__ ws, float* __restrict__ out) {
    const int t   = threadIdx.x;
    const int bid = blockIdx.x;                  // 1024
    const int b   = bid >> 7;
    const int rem = bid & 127;
    const int cg  = rem & 3;                     // col group
    const int rc  = rem >> 2;                    // row chunk
    const int col = cg * 256 + t;
    const int r0  = rc * CHB;

    const float* base = ws + (size_t)b * NH * NW + col;

    float ring[3][11];
    #pragma unroll
    for (int p = 0; p < 3; ++p)
        #pragma unroll
        for (int s = 0; s < 11; ++s) ring[p][s] = 0.f;
    float sxx = 0.f, syy = 0.f, sxy = 0.f;

    for (int g = 0; g < 4; ++g) {
        #pragma unroll
        for (int s = 0; s < 11; ++s) {           // static ring index
            const int k = g * 11 + s;
            if (k >= KSB) continue;              // uniform
            const int h = r0 - 5 + k;

            float vxx = 0.f, vyy = 0.f, vxy = 0.f;
            if (h >= 0 && h < NH) {              // scalar branch (h uniform)
                const size_t off = (size_t)h * NW;
                vxx = base[0 * WS_PLANE + off];
                vyy = base[1 * WS_PLANE + off];
                vxy = base[2 * WS_PLANE + off];
            }
            sxx += vxx - ring[0][s]; ring[0][s] = vxx;
            syy += vyy - ring[1][s]; ring[1][s] = vyy;
            sxy += vxy - ring[2][s]; ring[2][s] = vxy;

            if (k >= 10) {
                const int r = r0 + k - 10;
                const float den = __builtin_amdgcn_sqrtf(sxx) *
                                  __builtin_amdgcn_sqrtf(syy) + EPS;
                out[((size_t)b * NH + r) * NW + col] =
                    sxy * __builtin_amdgcn_rcpf(den);
            }
        }
    }
}

// ===================== FALLBACK: monolithic (round-4) =======================
#define BAND 128
#define CH 16
#define KSTEPS (CH + 10)
#define PADW 144

__global__ __launch_bounds__(64, 2)
void lcs_kernel(const float* __restrict__ x, const float* __restrict__ y,
                float* __restrict__ out) {
    __shared__ __align__(16) float P[3][PADW];

    const int l   = threadIdx.x;
    const int bid = blockIdx.x;
    const int b     = bid >> 9;
    const int rem   = bid & 511;
    const int band0 = (rem & 7) * BAND;
    const int r0    = (rem >> 3) * CH;

    const size_t chan = (size_t)NH * NW;
    const float* xb = x + (size_t)b * NC * chan;
    const float* yb = y + (size_t)b * NC * chan;

    const int gc0 = band0 - 8 + 2 * l;
    const int gcE = band0 + 120 + 2 * l;
    const float mm = (gc0 >= 0) ? 1.f : 0.f;
    const float me = (l < 8 && gcE + 1 <= NW - 1) ? 1.f : 0.f;
    const int o0 = (gc0 >= 0) ? gc0 : 0;
    const int oE = (me > 0.f) ? gcE : 0;

    float2 cur[12], nxt[12];
    auto ldrow = [&](int gr, float2* d) {
        const int rc = gr < 0 ? 0 : (gr > NH - 1 ? NH - 1 : gr);
        const size_t ro = (size_t)rc * NW;
        #pragma unroll
        for (int c = 0; c < 3; ++c) {
            const float* xr = xb + c * chan + ro;
            const float* yr = yb + c * chan + ro;
            d[c]     = *(const float2*)(xr + o0);
            d[3 + c] = *(const float2*)(yr + o0);
            d[6 + c] = *(const float2*)(xr + oE);
            d[9 + c] = *(const float2*)(yr + oE);
        }
    };

    ldrow(r0 - 5, cur);

    float2 ring[3][11];
    #pragma unroll
    for (int p = 0; p < 3; ++p)
        #pragma unroll
        for (int s = 0; s < 11; ++s) ring[p][s] = make_float2(0.f, 0.f);
    float2 vs[3] = {make_float2(0.f,0.f), make_float2(0.f,0.f), make_float2(0.f,0.f)};

    for (int g = 0; g < 3; ++g) {
        #pragma unroll
        for (int s = 0; s < 11; ++s) {
            const int k = g * 11 + s;
            if (k >= KSTEPS) continue;
            if (k + 1 < KSTEPS) ldrow(r0 - 4 + k, nxt);

            float2 pxx = make_float2(0.f,0.f), pyy = pxx, pxy = pxx;
            float2 qxx = pxx, qyy = pxx, qxy = pxx;
            #pragma unroll
            for (int c = 0; c < 3; ++c) {
                const float2 xm = cur[c],   ym = cur[3+c];
                const float2 xe = cur[6+c], ye = cur[9+c];
                pxx.x += xm.x*xm.x; pxx.y += xm.y*xm.y;
                pyy.x += ym.x*ym.x; pyy.y += ym.y*ym.y;
                pxy.x += xm.x*ym.x; pxy.y += xm.y*ym.y;
                qxx.x += xe.x*xe.x; qxx.y += xe.y*xe.y;
                qyy.x += ye.x*ye.x; qyy.y += ye.y*ye.y;
                qxy.x += xe.x*ye.x; qxy.y += xe.y*ye.y;
            }
            const int gr = r0 - 5 + k;
            const float rmf = (gr >= 0 && gr < NH) ? 1.f : 0.f;
            const float cmM = rmf * mm, cmE = rmf * me;
            pxx.x *= cmM; pxx.y *= cmM; pyy.x *= cmM; pyy.y *= cmM;
            pxy.x *= cmM; pxy.y *= cmM;
            qxx.x *= cmE; qxx.y *= cmE; qyy.x *= cmE; qyy.y *= cmE;
            qxy.x *= cmE; qxy.y *= cmE;

            ((float2*)&P[0][0])[l] = pxx;
            ((float2*)&P[1][0])[l] = pyy;
            ((float2*)&P[2][0])[l] = pxy;
            if (l < 8) {
                ((float2*)&P[0][0])[64 + l] = qxx;
                ((float2*)&P[1][0])[64 + l] = qyy;
                ((float2*)&P[2][0])[64 + l] = qxy;
            }
            __builtin_amdgcn_wave_barrier();

            #pragma unroll
            for (int p = 0; p < 3; ++p) {
                const float* Pp = &P[p][0];
                float2 tt[7];
                #pragma unroll
                for (int j = 0; j < 7; ++j)
                    tt[j] = *(const float2*)(Pp + 2*l + 2 + 2*j);
                float h0 = ((tt[0].y + tt[1].x) + (tt[1].y + tt[2].x))
                         + ((tt[2].y + tt[3].x) + (tt[3].y + tt[4].x))
                         + ((tt[4].y + tt[5].x) + tt[5].y);
                float h1 = h0 - tt[0].y + tt[6].x;
                vs[p].x += h0 - ring[p][s].x;
                vs[p].y += h1 - ring[p][s].y;
                ring[p][s].x = h0;
                ring[p][s].y = h1;
            }
            __builtin_amdgcn_wave_barrier();

            if (k >= 10) {
                const int orow = r0 + k - 10;
                const float d0 = __builtin_amdgcn_sqrtf(vs[0].x) *
                                 __builtin_amdgcn_sqrtf(vs[1].x) + EPS;
                const float d1 = __builtin_amdgcn_sqrtf(vs[0].y) *
                                 __builtin_amdgcn_sqrtf(vs[1].y) + EPS;
                float2 o;
                o.x = vs[2].x * __builtin_amdgcn_rcpf(d0);
                o.y = vs[2].y * __builtin_amdgcn_rcpf(d1);
                *(float2*)(out + ((size_t)b * NH + orow) * NW + band0 + 2*l) = o;
            }
            if (k + 1 < KSTEPS) {
                #pragma unroll
                for (int i = 0; i < 12; ++i) cur[i] = nxt[i];
            }
        }
    }
}

extern "C" void kernel_launch(void* const* d_in, const int* in_sizes, int n_in,
                              void* d_out, int out_size, void* d_ws, size_t ws_size,
                              hipStream_t stream) {
    const float* x = (const float*)d_in[0];
    const float* y = (const float*)d_in[1];
    float* out = (float*)d_out;

    const size_t need = (size_t)3 * NB * NH * NW * sizeof(float);  // 100.7 MB
    if (d_ws != nullptr && ws_size >= need) {
        float* ws = (float*)d_ws;
        lcs_hpass<<<dim3(NB * 256), dim3(256), 0, stream>>>(x, y, ws);
        lcs_vpass<<<dim3(1024),     dim3(256), 0, stream>>>(ws, out);
    } else {
        lcs_kernel<<<dim3(4096), dim3(64), 0, stream>>>(x, y, out);
    }
}

// Round 6
// 258.020 us; speedup vs baseline: 1.0106x; 1.0106x over previous
//
#include <hip/hip_runtime.h>
#include <math.h>

#define NB 8
#define NC 3
#define NH 1024
#define NW 1024
#define EPS 1e-6f

#define WS_PLANE ((size_t)NB * NH * NW)          // elems per H plane (8.39M)

// ============================ PASS A: horizontal ============================
// ONE ROW PER BLOCK (grid 8192): no row loop -> no serial load->barrier->load
// chain. All 6 float4 global loads issue in one burst, latency paid once per
// block; 4 resident blocks/CU overlap their chains -> BW-bound, not latency.
// Block = 256 threads = full 1024-col row (float4/lane).
// LDS per plane: [8 zero | 1024 | 8 zero]; col c <-> index 8+c.
__global__ __launch_bounds__(256, 4)
void lcs_hpass(const float* __restrict__ x, const float* __restrict__ y,
               float* __restrict__ ws) {
    __shared__ __align__(16) float Pp[3][1040];

    const int t   = threadIdx.x;                 // 0..255
    const int bid = blockIdx.x;                  // 0..8191
    const int b   = bid >> 10;                   // batch
    const int row = bid & 1023;

    const size_t chan = (size_t)NH * NW;
    const float* xb = x + (size_t)b * NC * chan;
    const float* yb = y + (size_t)b * NC * chan;
    float* wsb = ws + (size_t)b * chan;          // + p*WS_PLANE per plane
    const size_t ro = (size_t)row * NW + 4 * t;

    // ---- channel-reduced products for this lane's 4 cols (6 loads, 1 burst)
    float4 pxx = make_float4(0.f,0.f,0.f,0.f), pyy = pxx, pxy = pxx;
    #pragma unroll
    for (int c = 0; c < 3; ++c) {
        const float4 fx = *(const float4*)(xb + c * chan + ro);
        const float4 fy = *(const float4*)(yb + c * chan + ro);
        pxx.x += fx.x*fx.x; pxx.y += fx.y*fx.y; pxx.z += fx.z*fx.z; pxx.w += fx.w*fx.w;
        pyy.x += fy.x*fy.x; pyy.y += fy.y*fy.y; pyy.z += fy.z*fy.z; pyy.w += fy.w*fy.w;
        pxy.x += fx.x*fy.x; pxy.y += fx.y*fy.y; pxy.z += fx.z*fy.z; pxy.w += fx.w*fy.w;
    }

    // zero pads + publish products
    #pragma unroll
    for (int p = 0; p < 3; ++p) {
        if (t < 8) { Pp[p][t] = 0.f; Pp[p][1032 + t] = 0.f; }
    }
    *(float4*)&Pp[0][8 + 4*t] = pxx;
    *(float4*)&Pp[1][8 + 4*t] = pyy;
    *(float4*)&Pp[2][8 + 4*t] = pxy;
    __syncthreads();                             // single barrier per block

    // ---- horizontal 11-tap, 4 cols per lane (own products = B in regs) ----
    const float4 own[3] = {pxx, pyy, pxy};
    #pragma unroll
    for (int p = 0; p < 3; ++p) {
        const float* q = &Pp[p][0];
        const float  wm1 = q[4*t + 3];                    // col 4t-5
        const float4 A   = *(const float4*)(q + 4*t + 4); // cols 4t-4..4t-1
        const float4 B   = own[p];                        // cols 4t..4t+3
        const float4 C   = *(const float4*)(q + 4*t + 12);// cols 4t+4..4t+7
        const float  wp  = q[4*t + 16];                   // col 4t+8
        float4 h;
        h.x = wm1 + ((A.x + A.y) + (A.z + A.w))
                  + ((B.x + B.y) + (B.z + B.w)) + (C.x + C.y);
        h.y = h.x - wm1 + C.z;
        h.z = h.y - A.x + C.w;
        h.w = h.z - A.y + wp;
        *(float4*)(wsb + (size_t)p * WS_PLANE + ro) = h;
    }
}

// ============================ PASS B: vertical ==============================
// 1 col/lane, 256-thr blocks (256 cols), CHB=32 output rows/block.
// grid: 8 batches * 4 colgroups * 32 rowchunks = 1024 blocks.
// Ring = 3 planes x 11 scalars = 33 VGPR -> ~50 total -> 4 waves/SIMD.
#define CHB 32
#define KSB (CHB + 10)      // 42 H rows per chunk

__global__ __launch_bounds__(256, 4)
void lcs_vpass(const float* __restrict__ ws, float* __restrict__ out) {
    const int t   = threadIdx.x;
    const int bid = blockIdx.x;                  // 1024
    const int b   = bid >> 7;
    const int rem = bid & 127;
    const int cg  = rem & 3;                     // col group
    const int rc  = rem >> 2;                    // row chunk
    const int col = cg * 256 + t;
    const int r0  = rc * CHB;

    const float* base = ws + (size_t)b * NH * NW + col;

    float ring[3][11];
    #pragma unroll
    for (int p = 0; p < 3; ++p)
        #pragma unroll
        for (int s = 0; s < 11; ++s) ring[p][s] = 0.f;
    float sxx = 0.f, syy = 0.f, sxy = 0.f;

    for (int g = 0; g < 4; ++g) {
        #pragma unroll
        for (int s = 0; s < 11; ++s) {           // static ring index
            const int k = g * 11 + s;
            if (k >= KSB) continue;              // uniform
            const int h = r0 - 5 + k;

            float vxx = 0.f, vyy = 0.f, vxy = 0.f;
            if (h >= 0 && h < NH) {              // scalar branch (h uniform)
                const size_t off = (size_t)h * NW;
                vxx = base[0 * WS_PLANE + off];
                vyy = base[1 * WS_PLANE + off];
                vxy = base[2 * WS_PLANE + off];
            }
            sxx += vxx - ring[0][s]; ring[0][s] = vxx;
            syy += vyy - ring[1][s]; ring[1][s] = vyy;
            sxy += vxy - ring[2][s]; ring[2][s] = vxy;

            if (k >= 10) {
                const int r = r0 + k - 10;
                const float den = __builtin_amdgcn_sqrtf(sxx) *
                                  __builtin_amdgcn_sqrtf(syy) + EPS;
                out[((size_t)b * NH + r) * NW + col] =
                    sxy * __builtin_amdgcn_rcpf(den);
            }
        }
    }
}

// ===================== FALLBACK: monolithic (round-4) =======================
#define BAND 128
#define CH 16
#define KSTEPS (CH + 10)
#define PADW 144

__global__ __launch_bounds__(64, 2)
void lcs_kernel(const float* __restrict__ x, const float* __restrict__ y,
                float* __restrict__ out) {
    __shared__ __align__(16) float P[3][PADW];

    const int l   = threadIdx.x;
    const int bid = blockIdx.x;
    const int b     = bid >> 9;
    const int rem   = bid & 511;
    const int band0 = (rem & 7) * BAND;
    const int r0    = (rem >> 3) * CH;

    const size_t chan = (size_t)NH * NW;
    const float* xb = x + (size_t)b * NC * chan;
    const float* yb = y + (size_t)b * NC * chan;

    const int gc0 = band0 - 8 + 2 * l;
    const int gcE = band0 + 120 + 2 * l;
    const float mm = (gc0 >= 0) ? 1.f : 0.f;
    const float me = (l < 8 && gcE + 1 <= NW - 1) ? 1.f : 0.f;
    const int o0 = (gc0 >= 0) ? gc0 : 0;
    const int oE = (me > 0.f) ? gcE : 0;

    float2 cur[12], nxt[12];
    auto ldrow = [&](int gr, float2* d) {
        const int rc = gr < 0 ? 0 : (gr > NH - 1 ? NH - 1 : gr);
        const size_t ro = (size_t)rc * NW;
        #pragma unroll
        for (int c = 0; c < 3; ++c) {
            const float* xr = xb + c * chan + ro;
            const float* yr = yb + c * chan + ro;
            d[c]     = *(const float2*)(xr + o0);
            d[3 + c] = *(const float2*)(yr + o0);
            d[6 + c] = *(const float2*)(xr + oE);
            d[9 + c] = *(const float2*)(yr + oE);
        }
    };

    ldrow(r0 - 5, cur);

    float2 ring[3][11];
    #pragma unroll
    for (int p = 0; p < 3; ++p)
        #pragma unroll
        for (int s = 0; s < 11; ++s) ring[p][s] = make_float2(0.f, 0.f);
    float2 vs[3] = {make_float2(0.f,0.f), make_float2(0.f,0.f), make_float2(0.f,0.f)};

    for (int g = 0; g < 3; ++g) {
        #pragma unroll
        for (int s = 0; s < 11; ++s) {
            const int k = g * 11 + s;
            if (k >= KSTEPS) continue;
            if (k + 1 < KSTEPS) ldrow(r0 - 4 + k, nxt);

            float2 pxx = make_float2(0.f,0.f), pyy = pxx, pxy = pxx;
            float2 qxx = pxx, qyy = pxx, qxy = pxx;
            #pragma unroll
            for (int c = 0; c < 3; ++c) {
                const float2 xm = cur[c],   ym = cur[3+c];
                const float2 xe = cur[6+c], ye = cur[9+c];
                pxx.x += xm.x*xm.x; pxx.y += xm.y*xm.y;
                pyy.x += ym.x*ym.x; pyy.y += ym.y*ym.y;
                pxy.x += xm.x*ym.x; pxy.y += xm.y*ym.y;
                qxx.x += xe.x*xe.x; qxx.y += xe.y*xe.y;
                qyy.x += ye.x*ye.x; qyy.y += ye.y*ye.y;
                qxy.x += xe.x*ye.x; qxy.y += xe.y*ye.y;
            }
            const int gr = r0 - 5 + k;
            const float rmf = (gr >= 0 && gr < NH) ? 1.f : 0.f;
            const float cmM = rmf * mm, cmE = rmf * me;
            pxx.x *= cmM; pxx.y *= cmM; pyy.x *= cmM; pyy.y *= cmM;
            pxy.x *= cmM; pxy.y *= cmM;
            qxx.x *= cmE; qxx.y *= cmE; qyy.x *= cmE; qyy.y *= cmE;
            qxy.x *= cmE; qxy.y *= cmE;

            ((float2*)&P[0][0])[l] = pxx;
            ((float2*)&P[1][0])[l] = pyy;
            ((float2*)&P[2][0])[l] = pxy;
            if (l < 8) {
                ((float2*)&P[0][0])[64 + l] = qxx;
                ((float2*)&P[1][0])[64 + l] = qyy;
                ((float2*)&P[2][0])[64 + l] = qxy;
            }
            __builtin_amdgcn_wave_barrier();

            #pragma unroll
            for (int p = 0; p < 3; ++p) {
                const float* Pp = &P[p][0];
                float2 tt[7];
                #pragma unroll
                for (int j = 0; j < 7; ++j)
                    tt[j] = *(const float2*)(Pp + 2*l + 2 + 2*j);
                float h0 = ((tt[0].y + tt[1].x) + (tt[1].y + tt[2].x))
                         + ((tt[2].y + tt[3].x) + (tt[3].y + tt[4].x))
                         + ((tt[4].y + tt[5].x) + tt[5].y);
                float h1 = h0 - tt[0].y + tt[6].x;
                vs[p].x += h0 - ring[p][s].x;
                vs[p].y += h1 - ring[p][s].y;
                ring[p][s].x = h0;
                ring[p][s].y = h1;
            }
            __builtin_amdgcn_wave_barrier();

            if (k >= 10) {
                const int orow = r0 + k - 10;
                const float d0 = __builtin_amdgcn_sqrtf(vs[0].x) *
                                 __builtin_amdgcn_sqrtf(vs[1].x) + EPS;
                const float d1 = __builtin_amdgcn_sqrtf(vs[0].y) *
                                 __builtin_amdgcn_sqrtf(vs[1].y) + EPS;
                float2 o;
                o.x = vs[2].x * __builtin_amdgcn_rcpf(d0);
                o.y = vs[2].y * __builtin_amdgcn_rcpf(d1);
                *(float2*)(out + ((size_t)b * NH + orow) * NW + band0 + 2*l) = o;
            }
            if (k + 1 < KSTEPS) {
                #pragma unroll
                for (int i = 0; i < 12; ++i) cur[i] = nxt[i];
            }
        }
    }
}

extern "C" void kernel_launch(void* const* d_in, const int* in_sizes, int n_in,
                              void* d_out, int out_size, void* d_ws, size_t ws_size,
                              hipStream_t stream) {
    const float* x = (const float*)d_in[0];
    const float* y = (const float*)d_in[1];
    float* out = (float*)d_out;

    const size_t need = (size_t)3 * NB * NH * NW * sizeof(float);  // 100.7 MB
    if (d_ws != nullptr && ws_size >= need) {
        float* ws = (float*)d_ws;
        lcs_hpass<<<dim3(NB * NH), dim3(256), 0, stream>>>(x, y, ws);
        lcs_vpass<<<dim3(1024),    dim3(256), 0, stream>>>(ws, out);
    } else {
        lcs_kernel<<<dim3(4096), dim3(64), 0, stream>>>(x, y, out);
    }
}

// Round 8
// 253.973 us; speedup vs baseline: 1.0267x; 1.0159x over previous
//
#include <hip/hip_runtime.h>
#include <math.h>

#define NB 8
#define NC 3
#define NH 1024
#define NW 1024
#define EPS 1e-6f

#define BAND 128            // output cols per wave (float2 per lane)
#define CH 64               // output rows per wave (halo factor 74/64=1.16)
#define KSTEPS (CH + 10)    // 74 product rows per chunk
#define PADW 144            // 8 pad | 128 | 8 pad  (floats)
// grid: 8 batches * 8 bands * 16 chunks = 1024 blocks of 64 threads (1 wave).
// Empirical model (R2-R6): memory system plateaus at ~3.3-3.7 TB/s logical
// regardless of occupancy (7..24 waves/CU) -> minimize logical bytes.
// CH=64 cuts vertical halo re-reads: 330 -> 295 MB logical vs CH=32.

__global__ __launch_bounds__(64, 2)
void lcs_kernel(const float* __restrict__ x, const float* __restrict__ y,
                float* __restrict__ out) {
    __shared__ __align__(16) float P[3][PADW];   // 1728 B, wave-private

    const int l   = threadIdx.x;                 // 0..63
    const int bid = blockIdx.x;
    const int b     = bid >> 7;                  // batch (0..7)
    const int rem   = bid & 127;
    const int band0 = (rem & 7) * BAND;
    const int r0    = (rem >> 3) * CH;           // 16 chunks of 64 rows

    const size_t chan = (size_t)NH * NW;
    const float* xb = x + (size_t)b * NC * chan;
    const float* yb = y + (size_t)b * NC * chan;

    // lane column offsets (constant across steps) + edge masks folded to floats
    const int gc0 = band0 - 8 + 2 * l;                 // main float2 col
    const int gcE = band0 + 120 + 2 * l;               // extra float2 col (lanes 0..7)
    const float mm = (gc0 >= 0) ? 1.f : 0.f;           // left edge, band0==0 lanes 0..3
    const float me = (l < 8 && gcE + 1 <= NW - 1) ? 1.f : 0.f;
    const int o0 = (gc0 >= 0) ? gc0 : 0;               // clamped -> always valid
    const int oE = (me > 0.f) ? gcE : 0;

    float2 cur[12], nxt[12];
    // d[0..2]=x main ch, d[3..5]=y main, d[6..8]=x extra, d[9..11]=y extra
    auto ldrow = [&](int gr, float2* d) {
        const int rc = gr < 0 ? 0 : (gr > NH - 1 ? NH - 1 : gr);   // scalar clamp
        const size_t ro = (size_t)rc * NW;
        #pragma unroll
        for (int c = 0; c < 3; ++c) {
            const float* xr = xb + c * chan + ro;   // scalar base -> saddr form
            const float* yr = yb + c * chan + ro;
            d[c]     = *(const float2*)(xr + o0);
            d[3 + c] = *(const float2*)(yr + o0);
            d[6 + c] = *(const float2*)(xr + oE);
            d[9 + c] = *(const float2*)(yr + oE);
        }
    };

    ldrow(r0 - 5, cur);   // prime k=0

    float2 ring[3][11];
    #pragma unroll
    for (int p = 0; p < 3; ++p)
        #pragma unroll
        for (int s = 0; s < 11; ++s) ring[p][s] = make_float2(0.f, 0.f);
    float2 vs[3] = {make_float2(0.f,0.f), make_float2(0.f,0.f), make_float2(0.f,0.f)};

    for (int g = 0; g < 7; ++g) {                 // rolled (code stays ~11 steps)
        #pragma unroll
        for (int s = 0; s < 11; ++s) {            // unrolled -> static ring index
            const int k = g * 11 + s;
            if (k >= KSTEPS) continue;            // uniform, only g==6,s>=8

            // ---- prefetch next row first: max time in flight ----
            if (k + 1 < KSTEPS) ldrow(r0 - 4 + k, nxt);

            // ---- channel-reduced products of current row ----
            float2 pxx = make_float2(0.f,0.f), pyy = pxx, pxy = pxx;
            float2 qxx = pxx, qyy = pxx, qxy = pxx;
            #pragma unroll
            for (int c = 0; c < 3; ++c) {
                const float2 xm = cur[c],   ym = cur[3+c];
                const float2 xe = cur[6+c], ye = cur[9+c];
                pxx.x += xm.x*xm.x; pxx.y += xm.y*xm.y;
                pyy.x += ym.x*ym.x; pyy.y += ym.y*ym.y;
                pxy.x += xm.x*ym.x; pxy.y += xm.y*ym.y;
                qxx.x += xe.x*xe.x; qxx.y += xe.y*xe.y;
                qyy.x += ye.x*ye.x; qyy.y += ye.y*ye.y;
                qxy.x += xe.x*ye.x; qxy.y += xe.y*ye.y;
            }
            // fold row+lane OOB masks (values at clamped addrs are finite)
            const int gr = r0 - 5 + k;
            const float rmf = (gr >= 0 && gr < NH) ? 1.f : 0.f;   // scalar
            const float cmM = rmf * mm, cmE = rmf * me;
            pxx.x *= cmM; pxx.y *= cmM; pyy.x *= cmM; pyy.y *= cmM;
            pxy.x *= cmM; pxy.y *= cmM;
            qxx.x *= cmE; qxx.y *= cmE; qyy.x *= cmE; qyy.y *= cmE;
            qxy.x *= cmE; qxy.y *= cmE;

            ((float2*)&P[0][0])[l] = pxx;
            ((float2*)&P[1][0])[l] = pyy;
            ((float2*)&P[2][0])[l] = pxy;
            if (l < 8) {
                ((float2*)&P[0][0])[64 + l] = qxx;
                ((float2*)&P[1][0])[64 + l] = qyy;
                ((float2*)&P[2][0])[64 + l] = qxy;
            }
            __builtin_amdgcn_wave_barrier();   // pin LDS writes above reads

            // ---- horizontal 11-tap + vertical running sum (ring) ----
            #pragma unroll
            for (int p = 0; p < 3; ++p) {
                const float* Pp = &P[p][0];
                float2 t[7];
                #pragma unroll
                for (int j = 0; j < 7; ++j)
                    t[j] = *(const float2*)(Pp + 2*l + 2 + 2*j);
                float h0 = ((t[0].y + t[1].x) + (t[1].y + t[2].x))
                         + ((t[2].y + t[3].x) + (t[3].y + t[4].x))
                         + ((t[4].y + t[5].x) + t[5].y);
                float h1 = h0 - t[0].y + t[6].x;
                vs[p].x += h0 - ring[p][s].x;
                vs[p].y += h1 - ring[p][s].y;
                ring[p][s].x = h0;
                ring[p][s].y = h1;
            }
            __builtin_amdgcn_wave_barrier();   // pin reads above next step's writes

            // ---- emit ----
            if (k >= 10) {
                const int orow = r0 + k - 10;
                const float d0 = __builtin_amdgcn_sqrtf(vs[0].x) *
                                 __builtin_amdgcn_sqrtf(vs[1].x) + EPS;
                const float d1 = __builtin_amdgcn_sqrtf(vs[0].y) *
                                 __builtin_amdgcn_sqrtf(vs[1].y) + EPS;
                float2 o;
                o.x = vs[2].x * __builtin_amdgcn_rcpf(d0);
                o.y = vs[2].y * __builtin_amdgcn_rcpf(d1);
                *(float2*)(out + ((size_t)b * NH + orow) * NW + band0 + 2*l) = o;
            }

            // rotate prefetch regs (renamed across unrolled copies)
            if (k + 1 < KSTEPS) {
                #pragma unroll
                for (int i = 0; i < 12; ++i) cur[i] = nxt[i];
            }
        }
    }
}

extern "C" void kernel_launch(void* const* d_in, const int* in_sizes, int n_in,
                              void* d_out, int out_size, void* d_ws, size_t ws_size,
                              hipStream_t stream) {
    const float* x = (const float*)d_in[0];
    const float* y = (const float*)d_in[1];
    float* out = (float*)d_out;
    lcs_kernel<<<dim3(1024), dim3(64), 0, stream>>>(x, y, out);
}

// Round 11
// 241.285 us; speedup vs baseline: 1.0807x; 1.0526x over previous
//
#include <hip/hip_runtime.h>
#include <math.h>

#define NB 8
#define NC 3
#define NH 1024
#define NW 1024
#define EPS 1e-6f

#define BAND 128            // output cols per wave (float2 per lane)
#define CH 32               // output rows per wave
#define KSTEPS (CH + 10)    // 42 product rows per chunk
#define PADW 144            // 8 pad | 128 | 8 pad  (floats)
// grid: 8 batches * 8 bands * 32 chunks = 2048 blocks of 64 threads (1 wave).
// vs R2: LDS parity double-buffer removes the read->next-write WAR barrier;
// the ONE remaining wave_barrier (write->read) is correctness-required (the
// cross-lane RAW is invisible to per-thread alias analysis -- R10 failed
// without it). Step k+1's loads/products can now overlap step k's ds_read
// latency + h-sum chain.

__global__ __launch_bounds__(64, 2)
void lcs_kernel(const float* __restrict__ x, const float* __restrict__ y,
                float* __restrict__ out) {
    __shared__ __align__(16) float P[2][3][PADW];   // 3456 B, parity-buffered

    const int l   = threadIdx.x;                 // 0..63
    const int bid = blockIdx.x;
    const int b     = bid >> 8;                  // scalar (blockIdx-derived)
    const int rem   = bid & 255;
    const int band0 = (rem & 7) * BAND;
    const int r0    = (rem >> 3) * CH;

    const size_t chan = (size_t)NH * NW;
    const float* xb = x + (size_t)b * NC * chan;
    const float* yb = y + (size_t)b * NC * chan;

    // lane column offsets (constant across steps) + edge masks folded to floats
    const int gc0 = band0 - 8 + 2 * l;                 // main float2 col
    const int gcE = band0 + 120 + 2 * l;               // extra float2 col (lanes 0..7)
    const float mm = (gc0 >= 0) ? 1.f : 0.f;           // left edge, band0==0 lanes 0..3
    const float me = (l < 8 && gcE + 1 <= NW - 1) ? 1.f : 0.f;
    const int o0 = (gc0 >= 0) ? gc0 : 0;               // clamped -> always valid
    const int oE = (me > 0.f) ? gcE : 0;

    float2 cur[12], nx1[12], nx2[12];
    // d[0..2]=x main ch, d[3..5]=y main, d[6..8]=x extra, d[9..11]=y extra
    auto ldrow = [&](int gr, float2* d) {
        const int rc = gr < 0 ? 0 : (gr > NH - 1 ? NH - 1 : gr);   // scalar clamp
        const size_t ro = (size_t)rc * NW;
        #pragma unroll
        for (int c = 0; c < 3; ++c) {
            const float* xr = xb + c * chan + ro;   // scalar base -> saddr form
            const float* yr = yb + c * chan + ro;
            d[c]     = *(const float2*)(xr + o0);
            d[3 + c] = *(const float2*)(yr + o0);
            d[6 + c] = *(const float2*)(xr + oE);
            d[9 + c] = *(const float2*)(yr + oE);
        }
    };

    ldrow(r0 - 5, cur);   // prime k=0
    ldrow(r0 - 4, nx1);   // prime k=1

    float2 ring[3][11];
    #pragma unroll
    for (int p = 0; p < 3; ++p)
        #pragma unroll
        for (int s = 0; s < 11; ++s) ring[p][s] = make_float2(0.f, 0.f);
    float2 vs[3] = {make_float2(0.f,0.f), make_float2(0.f,0.f), make_float2(0.f,0.f)};

    for (int g = 0; g < 4; ++g) {                 // rolled (code stays ~11 steps)
        const int gg = g & 1;                     // k parity = (g&1)^(s&1), 11 odd
        #pragma unroll
        for (int s = 0; s < 11; ++s) {            // unrolled -> static ring index
            const int k = g * 11 + s;
            if (k >= KSTEPS) continue;            // uniform, only g==3,s>=9

            // ---- prefetch row k+2: ~2 step bodies in flight ----
            if (k + 2 < KSTEPS) ldrow(r0 - 3 + k, nx2);

            // ---- channel-reduced products of current row ----
            float2 pxx = make_float2(0.f,0.f), pyy = pxx, pxy = pxx;
            float2 qxx = pxx, qyy = pxx, qxy = pxx;
            #pragma unroll
            for (int c = 0; c < 3; ++c) {
                const float2 xm = cur[c],   ym = cur[3+c];
                const float2 xe = cur[6+c], ye = cur[9+c];
                pxx.x += xm.x*xm.x; pxx.y += xm.y*xm.y;
                pyy.x += ym.x*ym.x; pyy.y += ym.y*ym.y;
                pxy.x += xm.x*ym.x; pxy.y += xm.y*ym.y;
                qxx.x += xe.x*xe.x; qxx.y += xe.y*xe.y;
                qyy.x += ye.x*ye.x; qyy.y += ye.y*ye.y;
                qxy.x += xe.x*ye.x; qxy.y += xe.y*ye.y;
            }
            // fold row+lane OOB masks (values at clamped addrs are finite)
            const int gr = r0 - 5 + k;
            const float rmf = (gr >= 0 && gr < NH) ? 1.f : 0.f;   // scalar
            const float cmM = rmf * mm, cmE = rmf * me;
            pxx.x *= cmM; pxx.y *= cmM; pyy.x *= cmM; pyy.y *= cmM;
            pxy.x *= cmM; pxy.y *= cmM;
            qxx.x *= cmE; qxx.y *= cmE; qyy.x *= cmE; qyy.y *= cmE;
            qxy.x *= cmE; qxy.y *= cmE;

            // parity-selected LDS buffer: step s+1 writes the OTHER buffer,
            // so no read->write fence is needed; the single barrier below
            // covers the cross-lane write->read RAW.
            const int pp = gg ^ (s & 1);
            float* Pb = &P[pp][0][0];

            ((float2*)(Pb + 0*PADW))[l] = pxx;
            ((float2*)(Pb + 1*PADW))[l] = pyy;
            ((float2*)(Pb + 2*PADW))[l] = pxy;
            if (l < 8) {
                ((float2*)(Pb + 0*PADW))[64 + l] = qxx;
                ((float2*)(Pb + 1*PADW))[64 + l] = qyy;
                ((float2*)(Pb + 2*PADW))[64 + l] = qxy;
            }
            __builtin_amdgcn_wave_barrier();   // REQUIRED: cross-lane RAW fence

            // ---- horizontal 11-tap + vertical running sum (ring) ----
            #pragma unroll
            for (int p = 0; p < 3; ++p) {
                const float* Pq = Pb + p * PADW;
                float2 t[7];
                #pragma unroll
                for (int j = 0; j < 7; ++j)
                    t[j] = *(const float2*)(Pq + 2*l + 2 + 2*j);
                float h0 = ((t[0].y + t[1].x) + (t[1].y + t[2].x))
                         + ((t[2].y + t[3].x) + (t[3].y + t[4].x))
                         + ((t[4].y + t[5].x) + t[5].y);
                float h1 = h0 - t[0].y + t[6].x;
                vs[p].x += h0 - ring[p][s].x;
                vs[p].y += h1 - ring[p][s].y;
                ring[p][s].x = h0;
                ring[p][s].y = h1;
            }

            // ---- emit ----
            if (k >= 10) {
                const int orow = r0 + k - 10;
                const float d0 = __builtin_amdgcn_sqrtf(vs[0].x) *
                                 __builtin_amdgcn_sqrtf(vs[1].x) + EPS;
                const float d1 = __builtin_amdgcn_sqrtf(vs[0].y) *
                                 __builtin_amdgcn_sqrtf(vs[1].y) + EPS;
                float2 o;
                o.x = vs[2].x * __builtin_amdgcn_rcpf(d0);
                o.y = vs[2].y * __builtin_amdgcn_rcpf(d1);
                *(float2*)(out + ((size_t)b * NH + orow) * NW + band0 + 2*l) = o;
            }

            // rotate pipeline (renamed across unrolled copies)
            if (k + 1 < KSTEPS) {
                #pragma unroll
                for (int i = 0; i < 12; ++i) { cur[i] = nx1[i]; nx1[i] = nx2[i]; }
            }
        }
    }
}

extern "C" void kernel_launch(void* const* d_in, const int* in_sizes, int n_in,
                              void* d_out, int out_size, void* d_ws, size_t ws_size,
                              hipStream_t stream) {
    const float* x = (const float*)d_in[0];
    const float* y = (const float*)d_in[1];
    float* out = (float*)d_out;
    lcs_kernel<<<dim3(2048), dim3(64), 0, stream>>>(x, y, out);
}